// Round 1
// 274.174 us; speedup vs baseline: 1.0459x; 1.0459x over previous
//
#include <hip/hip_runtime.h>
#include <math.h>

#define DIV_UP(a,b) (((a)+(b)-1)/(b))

typedef __attribute__((ext_vector_type(8))) short bf16x8;
typedef __attribute__((ext_vector_type(4))) float f32x4;

// fp32 -> bf16 round-to-nearest-even
__device__ inline unsigned short f2b(float x) {
    unsigned int u = __float_as_uint(x);
    u += 0x7fffu + ((u >> 16) & 1u);
    return (unsigned short)(u >> 16);
}

// 8 packed bf16 (uint4) -> 8 floats
__device__ inline void cvt8(uint4 v, float* a) {
    a[0] = __uint_as_float(v.x << 16); a[1] = __uint_as_float(v.x & 0xffff0000u);
    a[2] = __uint_as_float(v.y << 16); a[3] = __uint_as_float(v.y & 0xffff0000u);
    a[4] = __uint_as_float(v.z << 16); a[5] = __uint_as_float(v.z & 0xffff0000u);
    a[6] = __uint_as_float(v.w << 16); a[7] = __uint_as_float(v.w & 0xffff0000u);
}

// deterministic float atomic max via sign-split int/uint monotone trick.
// Requires destination initialized to -inf (0xff800000).
__device__ inline void atomicMaxF(float* addr, float v) {
    if (v >= 0.f) atomicMax((int*)addr, __float_as_int(v));
    else          atomicMin((unsigned int*)addr, __float_as_uint(v));
}

// async global->LDS 16B
__device__ inline void gl16(void* lds, const void* g) {
    __builtin_amdgcn_global_load_lds(
        (const __attribute__((address_space(1))) void*)g,
        (__attribute__((address_space(3))) void*)lds, 16, 0, 0);
}

__global__ void k_zero_i(int* p, int n) {
    int i = blockIdx.x * blockDim.x + threadIdx.x;
    if (i < n) p[i] = 0;
}

__global__ void k_hist(const int* __restrict__ dst, int* __restrict__ hist, int E) {
    int i = blockIdx.x * blockDim.x + threadIdx.x;
    if (i < E) atomicAdd(&hist[dst[i]], 1);
}

// ---- hierarchical scan ----
__global__ __launch_bounds__(256) void k_scan_bsum(const int* __restrict__ hist,
                                                   int* __restrict__ bsum, int N) {
    __shared__ int red[256];
    int t = threadIdx.x;
    int base = blockIdx.x * 1024 + t * 4;
    int s = 0;
    if (base + 3 < N) {
        int4 v = *(const int4*)&hist[base];
        s = v.x + v.y + v.z + v.w;
    } else {
        for (int j = 0; j < 4; ++j) if (base + j < N) s += hist[base + j];
    }
    red[t] = s;
    __syncthreads();
    for (int off = 128; off >= 1; off >>= 1) {
        if (t < off) red[t] += red[t + off];
        __syncthreads();
    }
    if (t == 0) bsum[blockIdx.x] = red[0];
}

__global__ __launch_bounds__(1024) void k_scan_boff(const int* __restrict__ bsum,
        int* __restrict__ boff, int* __restrict__ row_off, int NB, int N) {
    __shared__ int s[1024];
    int t = threadIdx.x;
    int v = (t < NB) ? bsum[t] : 0;
    s[t] = v;
    __syncthreads();
    for (int off = 1; off < 1024; off <<= 1) {
        int u = (t >= off) ? s[t - off] : 0;
        __syncthreads();
        s[t] += u;
        __syncthreads();
    }
    if (t < NB) boff[t] = s[t] - v;
    if (t == NB - 1) row_off[N] = s[t];
}

// scan apply + dinv fused
__global__ __launch_bounds__(256) void k_scan_apply(const int* __restrict__ hist,
        const int* __restrict__ boff, int* __restrict__ row_off,
        float* __restrict__ dinv, int N) {
    __shared__ int s[256];
    int t = threadIdx.x;
    int base = blockIdx.x * 1024 + t * 4;
    int v[4];
    int loc = 0;
#pragma unroll
    for (int j = 0; j < 4; ++j) { v[j] = (base + j < N) ? hist[base + j] : 0; loc += v[j]; }
    s[t] = loc;
    __syncthreads();
    for (int off = 1; off < 256; off <<= 1) {
        int u = (t >= off) ? s[t - off] : 0;
        __syncthreads();
        s[t] += u;
        __syncthreads();
    }
    int run = boff[blockIdx.x] + s[t] - loc;
#pragma unroll
    for (int j = 0; j < 4; ++j) {
        if (base + j < N) {
            row_off[base + j] = run;
            dinv[base + j] = rsqrtf((float)(v[j] + 1));
        }
        run += v[j];
    }
}

__global__ void k_bin(const int* __restrict__ src, const int* __restrict__ dst,
                      const int* __restrict__ row_off, int* __restrict__ cursor,
                      const float* __restrict__ dinv,
                      int* __restrict__ csr_src, float* __restrict__ csr_w, int E) {
    int i = blockIdx.x * blockDim.x + threadIdx.x;
    if (i >= E) return;
    int d = dst[i], s = src[i];
    int pos = row_off[d] + atomicAdd(&cursor[d], 1);
    csr_src[pos] = s;
    csr_w[pos] = dinv[s] * dinv[d];
}

// fused preprocessing, block-range partitioned:
//   blocks [0,11):        head-weight collapse (WcT = (W3@W4@W5)^T, bc chain)
//   blocks [11,11+nfo):   fill d_out (out + out_emb) with -inf for atomic-max
//   blocks [11+nfo, ...): x->bf16, W1^T->bf16, W2^T->bf16
__global__ __launch_bounds__(256) void k_pre(
        const float* __restrict__ W3, const float* __restrict__ W4,
        const float* __restrict__ W5, const float* __restrict__ b3,
        const float* __restrict__ b4, const float* __restrict__ b5,
        float* __restrict__ WcT, float* __restrict__ bc,
        unsigned* __restrict__ outp, int nout, int nfo,
        const float* __restrict__ x, unsigned short* __restrict__ xb, int n4,
        const float* __restrict__ W1, unsigned short* __restrict__ w1t, int K1, int N1,
        const float* __restrict__ W2, unsigned short* __restrict__ w2t, int K2, int N2) {
    int b = blockIdx.x;
    int t = threadIdx.x;
    if (b < 11) {
        int c = b;
        if (c < 10) {
            __shared__ float Tc[128];
            if (t < 128) {
                float s = 0.f;
#pragma unroll 8
                for (int k = 0; k < 32; ++k) s = fmaf(W4[t * 32 + k], W5[k * 10 + c], s);
                Tc[t] = s;
            }
            __syncthreads();
            float s = 0.f;
            const float* w3r = &W3[t * 128];
#pragma unroll 8
            for (int j = 0; j < 128; ++j) s = fmaf(w3r[j], Tc[j], s);
            WcT[c * 256 + t] = s;
        } else {
            __shared__ float v[32];
            if (t < 32) {
                float s = b4[t];
                for (int j = 0; j < 128; ++j) s = fmaf(b3[j], W4[j * 32 + t], s);
                v[t] = s;
            }
            __syncthreads();
            if (t < 10) {
                float s = b5[t];
                for (int k = 0; k < 32; ++k) s = fmaf(v[k], W5[k * 10 + t], s);
                bc[t] = s;
            }
        }
        return;
    }
    if (b < 11 + nfo) {
        int i = (b - 11) * 256 + t;
        if (i < nout) outp[i] = 0xff800000u;   // -inf
        return;
    }
    int i = (b - 11 - nfo) * 256 + t;
    if (i < n4) {
        float4 v = ((const float4*)x)[i];
        ushort4 o;
        o.x = f2b(v.x); o.y = f2b(v.y); o.z = f2b(v.z); o.w = f2b(v.w);
        ((ushort4*)xb)[i] = o;
        return;
    }
    i -= n4;
    if (i < K1 * N1) {
        int k = i / N1, n = i % N1;
        w1t[(size_t)n * K1 + k] = f2b(W1[i]);
        return;
    }
    i -= K1 * N1;
    if (i < K2 * N2) {
        int k = i / N2, n = i % N2;
        w2t[(size_t)n * K2 + k] = f2b(W2[i]);
    }
}

// gather-aggregate over dst-CSR, bf16 in/out, ILP-4 edge loop.
template <int F>
__global__ __launch_bounds__(256) void k_gather_b(const unsigned short* __restrict__ H,
        const int* __restrict__ row_off, const int* __restrict__ csr_src,
        const float* __restrict__ csr_w, const float* __restrict__ dinv,
        const float* __restrict__ bias, unsigned short* __restrict__ outb, int N) {
    const int LPN = F / 8;
    const int NPB = 256 / LPN;
    int node = blockIdx.x * NPB + threadIdx.x / LPN;
    if (node >= N) return;
    int f = (threadIdx.x % LPN) * 8;
    const unsigned short* Hf = H + f;
    float sc = dinv[node]; sc *= sc;
    float a[8];
    cvt8(*(const uint4*)&Hf[(size_t)node * F], a);
#pragma unroll
    for (int j = 0; j < 8; ++j) a[j] *= sc;
    if (bias) {
#pragma unroll
        for (int j = 0; j < 8; ++j) a[j] += bias[f + j];
    }
    int e0 = row_off[node], e1 = row_off[node + 1];
    int e = e0;
    for (; e + 4 <= e1; e += 4) {
        int s0 = csr_src[e + 0], s1 = csr_src[e + 1];
        int s2 = csr_src[e + 2], s3 = csr_src[e + 3];
        uint4 v0 = *(const uint4*)&Hf[(size_t)s0 * F];
        uint4 v1 = *(const uint4*)&Hf[(size_t)s1 * F];
        uint4 v2 = *(const uint4*)&Hf[(size_t)s2 * F];
        uint4 v3 = *(const uint4*)&Hf[(size_t)s3 * F];
        float w0 = csr_w[e + 0], w1 = csr_w[e + 1];
        float w2 = csr_w[e + 2], w3 = csr_w[e + 3];
        float b0[8], b1[8], b2[8], b3[8];
        cvt8(v0, b0); cvt8(v1, b1); cvt8(v2, b2); cvt8(v3, b3);
#pragma unroll
        for (int j = 0; j < 8; ++j) {
            a[j] = fmaf(w0, b0[j], a[j]);
            a[j] = fmaf(w1, b1[j], a[j]);
            a[j] = fmaf(w2, b2[j], a[j]);
            a[j] = fmaf(w3, b3[j], a[j]);
        }
    }
    for (; e < e1; ++e) {
        int s = csr_src[e];
        float w = csr_w[e];
        float b[8];
        cvt8(*(const uint4*)&Hf[(size_t)s * F], b);
#pragma unroll
        for (int j = 0; j < 8; ++j) a[j] = fmaf(w, b[j], a[j]);
    }
    uint4 o;
    o.x = (unsigned)f2b(a[0]) | ((unsigned)f2b(a[1]) << 16);
    o.y = (unsigned)f2b(a[2]) | ((unsigned)f2b(a[3]) << 16);
    o.z = (unsigned)f2b(a[4]) | ((unsigned)f2b(a[5]) << 16);
    o.w = (unsigned)f2b(a[6]) | ((unsigned)f2b(a[7]) << 16);
    *(uint4*)&outb[(size_t)node * F + f] = o;
}

// terminal fused kernel: gather layer-2 aggregate (F=256, 8 nodes/block,
// 32 lanes/node), then — with h2 still in registers —
//   z = h2 @ Wc + bc  -> shfl-reduce -> run-coalesced atomicMaxF into out[g,:10]
//   feature-wise segment_max of h2 via LDS tile -> atomicMaxF into out_emb[g,:256]
// h2 is never written to global; out/out_emb must be pre-filled with -inf.
__global__ __launch_bounds__(256) void k_gather_head(
        const unsigned short* __restrict__ H,
        const int* __restrict__ row_off, const int* __restrict__ csr_src,
        const float* __restrict__ csr_w, const float* __restrict__ dinv,
        const float* __restrict__ bias, const int* __restrict__ batch,
        const float* __restrict__ WcT, const float* __restrict__ bc,
        float* __restrict__ out, float* __restrict__ out_emb, int N) {
    __shared__ __align__(16) float Ws[10][260];
    __shared__ float bs[10];
    __shared__ __align__(16) float h2s[8][264];
    __shared__ float zl[8][10];
    __shared__ int gl[8];
    int t = threadIdx.x;
    for (int i = t; i < 2560; i += 256) Ws[i >> 8][i & 255] = WcT[i];
    if (t < 10) bs[t] = bc[t];
    int nl = t >> 5;          // node within block, 0..7
    int q  = t & 31;          // lane within node group
    int node = blockIdx.x * 8 + nl;
    bool valid = node < N;
    if (q == 0) gl[nl] = valid ? batch[node] : -1;
    int f = q * 8;
    const unsigned short* Hf = H + f;
    float a[8] = {0.f, 0.f, 0.f, 0.f, 0.f, 0.f, 0.f, 0.f};
    if (valid) {
        float sc = dinv[node]; sc *= sc;
        cvt8(*(const uint4*)&Hf[(size_t)node * 256], a);
#pragma unroll
        for (int j = 0; j < 8; ++j) a[j] = fmaf(a[j], sc, bias[f + j]);
        int e0 = row_off[node], e1 = row_off[node + 1];
        int e = e0;
        for (; e + 4 <= e1; e += 4) {
            int s0 = csr_src[e + 0], s1 = csr_src[e + 1];
            int s2 = csr_src[e + 2], s3 = csr_src[e + 3];
            uint4 v0 = *(const uint4*)&Hf[(size_t)s0 * 256];
            uint4 v1 = *(const uint4*)&Hf[(size_t)s1 * 256];
            uint4 v2 = *(const uint4*)&Hf[(size_t)s2 * 256];
            uint4 v3 = *(const uint4*)&Hf[(size_t)s3 * 256];
            float w0 = csr_w[e + 0], w1 = csr_w[e + 1];
            float w2 = csr_w[e + 2], w3 = csr_w[e + 3];
            float b0[8], b1[8], b2v[8], b3v[8];
            cvt8(v0, b0); cvt8(v1, b1); cvt8(v2, b2v); cvt8(v3, b3v);
#pragma unroll
            for (int j = 0; j < 8; ++j) {
                a[j] = fmaf(w0, b0[j], a[j]);
                a[j] = fmaf(w1, b1[j], a[j]);
                a[j] = fmaf(w2, b2v[j], a[j]);
                a[j] = fmaf(w3, b3v[j], a[j]);
            }
        }
        for (; e < e1; ++e) {
            int s = csr_src[e];
            float w = csr_w[e];
            float bv[8];
            cvt8(*(const uint4*)&Hf[(size_t)s * 256], bv);
#pragma unroll
            for (int j = 0; j < 8; ++j) a[j] = fmaf(w, bv[j], a[j]);
        }
    }
    __syncthreads();   // Ws/bs staged (and gl visible)

    // head dots: p[c] = sum over this lane's 8 features
#pragma unroll
    for (int c = 0; c < 10; ++c) {
        float4 wa = *(const float4*)&Ws[c][f];
        float4 wb = *(const float4*)&Ws[c][f + 4];
        float s = a[0] * wa.x;
        s = fmaf(a[1], wa.y, s);
        s = fmaf(a[2], wa.z, s);
        s = fmaf(a[3], wa.w, s);
        s = fmaf(a[4], wb.x, s);
        s = fmaf(a[5], wb.y, s);
        s = fmaf(a[6], wb.z, s);
        s = fmaf(a[7], wb.w, s);
        // sum across the node's 32 lanes (masks <32 stay within the group)
        s += __shfl_xor(s, 16);
        s += __shfl_xor(s, 8);
        s += __shfl_xor(s, 4);
        s += __shfl_xor(s, 2);
        s += __shfl_xor(s, 1);
        if (q == 0) zl[nl][c] = s + bs[c];
    }
    // stage h2 tile for feature-wise reduction
    *(float4*)&h2s[nl][f]     = make_float4(a[0], a[1], a[2], a[3]);
    *(float4*)&h2s[nl][f + 4] = make_float4(a[4], a[5], a[6], a[7]);
    __syncthreads();

    // out_emb: thread t owns feature t; run-coalesced atomics (batch-sorted)
    {
        int curg = -1; float m = 0.f;
#pragma unroll
        for (int n = 0; n < 8; ++n) {
            int g = gl[n];
            if (g < 0) continue;
            float v = h2s[n][t];
            if (g != curg) {
                if (curg >= 0) atomicMaxF(&out_emb[(size_t)curg * 256 + t], m);
                curg = g; m = v;
            } else {
                m = fmaxf(m, v);
            }
        }
        if (curg >= 0) atomicMaxF(&out_emb[(size_t)curg * 256 + t], m);
    }
    // out: thread t<10 owns head column t
    if (t < 10) {
        int curg = -1; float m = 0.f;
#pragma unroll
        for (int n = 0; n < 8; ++n) {
            int g = gl[n];
            if (g < 0) continue;
            float v = zl[n][t];
            if (g != curg) {
                if (curg >= 0) atomicMaxF(&out[(size_t)curg * 10 + t], m);
                curg = g; m = v;
            } else {
                m = fmaxf(m, v);
            }
        }
        if (curg >= 0) atomicMaxF(&out[(size_t)curg * 10 + t], m);
    }
}

// bf16 MFMA GEMM, fat-N tile: 128x256 per block, 512 threads = 8 waves (2x4),
// each wave 64x64 via 4x4 grid of 16x16x32 MFMAs, BK=64, global_load_lds w16,
// XOR-swizzled LDS, operand-swap mfma (lane = row + 4 contiguous cols).
template <int OUT_BF16, int ACT>
__global__ __launch_bounds__(512) void k_gemm_mfma256(const unsigned short* __restrict__ A,
        const unsigned short* __restrict__ Bt, const float* __restrict__ bias,
        void* __restrict__ Cout, int M, int K, int NC) {
    __shared__ __align__(16) unsigned short As[128][64];   // 16 KB
    __shared__ __align__(16) unsigned short Bs[256][64];   // 32 KB
    int tid = threadIdx.x;
    int wave = tid >> 6, lane = tid & 63;
    int row0 = blockIdx.y * 128, col0 = blockIdx.x * 256;
    int wr = (wave >> 2) * 64, wc = (wave & 3) * 64;
    f32x4 acc[4][4] = {};
    int lr = lane & 15;
    int lg = lane >> 4;
    int sw = ((lane & 7) ^ (lane >> 3)) << 3;
    int ch0 = (lg ^ (lr & 7)) << 3;
    int ch1 = ch0 ^ (4 << 3);

    for (int k0 = 0; k0 < K; k0 += 64) {
        // stage A: 2 rounds x (8 waves x 8 rows), B: 4 rounds
#pragma unroll
        for (int c = 0; c < 2; ++c) {
            int rl = c * 64 + wave * 8 + (lane >> 3);
            int gr = min(row0 + rl, M - 1);
            gl16(&As[c * 64 + wave * 8][0], &A[(size_t)gr * K + k0 + sw]);
        }
#pragma unroll
        for (int c = 0; c < 4; ++c) {
            int rl = c * 64 + wave * 8 + (lane >> 3);
            gl16(&Bs[c * 64 + wave * 8][0], &Bt[(size_t)(col0 + rl) * K + k0 + sw]);
        }
        __syncthreads();
        bf16x8 af[2][4], bv[2][4];
#pragma unroll
        for (int i = 0; i < 4; ++i) {
            int ra = wr + i * 16 + lr;
            int rb = wc + i * 16 + lr;
            af[0][i] = *(const bf16x8*)&As[ra][ch0];
            af[1][i] = *(const bf16x8*)&As[ra][ch1];
            bv[0][i] = *(const bf16x8*)&Bs[rb][ch0];
            bv[1][i] = *(const bf16x8*)&Bs[rb][ch1];
        }
#pragma unroll
        for (int s = 0; s < 2; ++s)
#pragma unroll
            for (int i = 0; i < 4; ++i)
#pragma unroll
                for (int j = 0; j < 4; ++j)
                    acc[i][j] = __builtin_amdgcn_mfma_f32_16x16x32_bf16(bv[s][j], af[s][i], acc[i][j], 0, 0, 0);
        __syncthreads();
    }

    int q4 = lg * 4;
    float4 bb[4];
#pragma unroll
    for (int j = 0; j < 4; ++j)
        bb[j] = bias ? *(const float4*)&bias[col0 + wc + j * 16 + q4]
                     : make_float4(0.f, 0.f, 0.f, 0.f);
#pragma unroll
    for (int i = 0; i < 4; ++i) {
        int row = row0 + wr + i * 16 + lr;
        if (row >= M) continue;
#pragma unroll
        for (int j = 0; j < 4; ++j) {
            int c0 = col0 + wc + j * 16 + q4;
            float4 v;
            v.x = acc[i][j][0] + bb[j].x;
            v.y = acc[i][j][1] + bb[j].y;
            v.z = acc[i][j][2] + bb[j].z;
            v.w = acc[i][j][3] + bb[j].w;
            if (ACT) {
                v.x = (v.x >= 0.f) ? v.x : 0.01f * v.x;
                v.y = (v.y >= 0.f) ? v.y : 0.01f * v.y;
                v.z = (v.z >= 0.f) ? v.z : 0.01f * v.z;
                v.w = (v.w >= 0.f) ? v.w : 0.01f * v.w;
            }
            if (OUT_BF16) {
                uint2 o;
                o.x = (unsigned)f2b(v.x) | ((unsigned)f2b(v.y) << 16);
                o.y = (unsigned)f2b(v.z) | ((unsigned)f2b(v.w) << 16);
                *(uint2*)&((unsigned short*)Cout)[(size_t)row * NC + c0] = o;
            } else {
                *(float4*)&((float*)Cout)[(size_t)row * NC + c0] = v;
            }
        }
    }
}

extern "C" void kernel_launch(void* const* d_in, const int* in_sizes, int n_in,
                              void* d_out, int out_size, void* d_ws, size_t ws_size,
                              hipStream_t stream) {
    const float* x  = (const float*)d_in[0];
    const int* ei   = (const int*)d_in[1];
    const int* batch= (const int*)d_in[2];
    const float* W1 = (const float*)d_in[3];
    const float* b1 = (const float*)d_in[4];
    const float* W2 = (const float*)d_in[5];
    const float* b2 = (const float*)d_in[6];
    const float* W3 = (const float*)d_in[7];
    const float* b3 = (const float*)d_in[8];
    const float* W4 = (const float*)d_in[9];
    const float* b4 = (const float*)d_in[10];
    const float* W5 = (const float*)d_in[11];
    const float* b5 = (const float*)d_in[12];

    const int N  = in_sizes[2];           // 50000
    const int F  = in_sizes[0] / N;       // 128
    const int E  = in_sizes[1] / 2;       // 400000
    const int C1 = in_sizes[4];           // 512
    const int C2 = in_sizes[6];           // 256
    const int C5 = in_sizes[12];          // 10
    const int G  = out_size / (C2 + C5);  // 512
    const int NB = DIV_UP(N, 1024);

    const int* srcp = ei;
    const int* dstp = ei + E;

    // ---- workspace layout (256B-aligned carve-outs) ----
    uintptr_t p = (uintptr_t)d_ws;
    auto carve = [&](size_t bytes) {
        uintptr_t r = p;
        p += (bytes + 255) & ~(size_t)255;
        return (void*)r;
    };
    int* hist    = (int*)carve(sizeof(int) * N);
    int* cursor  = (int*)carve(sizeof(int) * N);      // MUST follow hist (joint zero-fill)
    int* row_off = (int*)carve(sizeof(int) * (N + 1));
    int* bsum    = (int*)carve(sizeof(int) * NB);
    int* boff    = (int*)carve(sizeof(int) * NB);
    int* csr_src = (int*)carve(sizeof(int) * E);
    float* csr_w = (float*)carve(sizeof(float) * E);
    float* dinv  = (float*)carve(sizeof(float) * N);
    float* wct   = (float*)carve(sizeof(float) * C2 * C5);
    float* bcv   = (float*)carve(sizeof(float) * C5);
    unsigned short* w1t = (unsigned short*)carve(sizeof(short) * F * C1);
    unsigned short* w2t = (unsigned short*)carve(sizeof(short) * C1 * C2);
    unsigned short* xb    = (unsigned short*)carve(sizeof(short) * (size_t)N * F);
    unsigned short* aggxb = (unsigned short*)carve(sizeof(short) * (size_t)N * F);
    unsigned short* h1b   = (unsigned short*)carve(sizeof(short) * (size_t)N * C1);
    unsigned short* t2b   = (unsigned short*)carve(sizeof(short) * (size_t)N * C2);

    float* out     = (float*)d_out;
    float* out_emb = out + (size_t)G * C5;

    // ---- CSR build + fused preprocessing ----
    int zspan = (int)(((sizeof(int) * N + 255) & ~(size_t)255) / 4) + N;  // hist..cursor
    k_zero_i<<<DIV_UP(zspan, 256), 256, 0, stream>>>(hist, zspan);
    k_hist<<<DIV_UP(E, 256), 256, 0, stream>>>(dstp, hist, E);
    k_scan_bsum<<<NB, 256, 0, stream>>>(hist, bsum, N);
    k_scan_boff<<<1, 1024, 0, stream>>>(bsum, boff, row_off, NB, N);
    k_scan_apply<<<NB, 256, 0, stream>>>(hist, boff, row_off, dinv, N);
    k_bin<<<DIV_UP(E, 256), 256, 0, stream>>>(srcp, dstp, row_off, cursor, dinv,
                                              csr_src, csr_w, E);

    int n4 = N * F / 4;
    int nout = G * (C2 + C5);
    int nfo = DIV_UP(nout, 256);
    int prep_total = n4 + F * C1 + C1 * C2;
    int pre_blocks = 11 + nfo + DIV_UP(prep_total, 256);
    k_pre<<<pre_blocks, 256, 0, stream>>>(W3, W4, W5, b3, b4, b5, wct, bcv,
                                          (unsigned*)d_out, nout, nfo,
                                          x, xb, n4, W1, w1t, F, C1, W2, w2t, C1, C2);

    // ---- layer 1: gather (bf16) -> fat-N MFMA GEMM + bias + leakyrelu -> h1 bf16 ----
    k_gather_b<128><<<DIV_UP(N, 16), 256, 0, stream>>>(
        xb, row_off, csr_src, csr_w, dinv, nullptr, aggxb, N);
    dim3 g1(C1 / 256, DIV_UP(N, 128));
    k_gemm_mfma256<1, 1><<<g1, 512, 0, stream>>>(aggxb, w1t, b1, h1b, N, F, C1);

    // ---- layer 2: fat-N MFMA GEMM -> t2 bf16 ----
    dim3 g2(C2 / 256, DIV_UP(N, 128));
    k_gemm_mfma256<1, 0><<<g2, 512, 0, stream>>>(h1b, w2t, nullptr, t2b, N, C1, C2);

    // ---- terminal fused: gather(+b2) -> head dots -> both segment_maxes ----
    k_gather_head<<<DIV_UP(N, 8), 256, 0, stream>>>(
        t2b, row_off, csr_src, csr_w, dinv, b2, batch, wct, bcv,
        out, out_emb, N);
}

// Round 2
// 271.803 us; speedup vs baseline: 1.0550x; 1.0087x over previous
//
#include <hip/hip_runtime.h>
#include <math.h>

#define DIV_UP(a,b) (((a)+(b)-1)/(b))

typedef __attribute__((ext_vector_type(8))) short bf16x8;
typedef __attribute__((ext_vector_type(4))) float f32x4;

// fp32 -> bf16 round-to-nearest-even
__device__ inline unsigned short f2b(float x) {
    unsigned int u = __float_as_uint(x);
    u += 0x7fffu + ((u >> 16) & 1u);
    return (unsigned short)(u >> 16);
}

// 8 packed bf16 (uint4) -> 8 floats
__device__ inline void cvt8(uint4 v, float* a) {
    a[0] = __uint_as_float(v.x << 16); a[1] = __uint_as_float(v.x & 0xffff0000u);
    a[2] = __uint_as_float(v.y << 16); a[3] = __uint_as_float(v.y & 0xffff0000u);
    a[4] = __uint_as_float(v.z << 16); a[5] = __uint_as_float(v.z & 0xffff0000u);
    a[6] = __uint_as_float(v.w << 16); a[7] = __uint_as_float(v.w & 0xffff0000u);
}

// deterministic float atomic max via sign-split int/uint monotone trick.
// Requires destination initialized to -inf (0xff800000).
__device__ inline void atomicMaxF(float* addr, float v) {
    if (v >= 0.f) atomicMax((int*)addr, __float_as_int(v));
    else          atomicMin((unsigned int*)addr, __float_as_uint(v));
}

// async global->LDS 16B
__device__ inline void gl16(void* lds, const void* g) {
    __builtin_amdgcn_global_load_lds(
        (const __attribute__((address_space(1))) void*)g,
        (__attribute__((address_space(3))) void*)lds, 16, 0, 0);
}

__global__ void k_zero_i(int* p, int n) {
    int i = blockIdx.x * blockDim.x + threadIdx.x;
    if (i < n) p[i] = 0;
}

__global__ void k_hist(const int* __restrict__ dst, int* __restrict__ hist, int E) {
    int i = blockIdx.x * blockDim.x + threadIdx.x;
    if (i < E) atomicAdd(&hist[dst[i]], 1);
}

// ---- hierarchical scan ----
__global__ __launch_bounds__(256) void k_scan_bsum(const int* __restrict__ hist,
                                                   int* __restrict__ bsum, int N) {
    __shared__ int red[256];
    int t = threadIdx.x;
    int base = blockIdx.x * 1024 + t * 4;
    int s = 0;
    if (base + 3 < N) {
        int4 v = *(const int4*)&hist[base];
        s = v.x + v.y + v.z + v.w;
    } else {
        for (int j = 0; j < 4; ++j) if (base + j < N) s += hist[base + j];
    }
    red[t] = s;
    __syncthreads();
    for (int off = 128; off >= 1; off >>= 1) {
        if (t < off) red[t] += red[t + off];
        __syncthreads();
    }
    if (t == 0) bsum[blockIdx.x] = red[0];
}

__global__ __launch_bounds__(1024) void k_scan_boff(const int* __restrict__ bsum,
        int* __restrict__ boff, int* __restrict__ row_off, int NB, int N) {
    __shared__ int s[1024];
    int t = threadIdx.x;
    int v = (t < NB) ? bsum[t] : 0;
    s[t] = v;
    __syncthreads();
    for (int off = 1; off < 1024; off <<= 1) {
        int u = (t >= off) ? s[t - off] : 0;
        __syncthreads();
        s[t] += u;
        __syncthreads();
    }
    if (t < NB) boff[t] = s[t] - v;
    if (t == NB - 1) row_off[N] = s[t];
}

// scan apply + dinv fused
__global__ __launch_bounds__(256) void k_scan_apply(const int* __restrict__ hist,
        const int* __restrict__ boff, int* __restrict__ row_off,
        float* __restrict__ dinv, int N) {
    __shared__ int s[256];
    int t = threadIdx.x;
    int base = blockIdx.x * 1024 + t * 4;
    int v[4];
    int loc = 0;
#pragma unroll
    for (int j = 0; j < 4; ++j) { v[j] = (base + j < N) ? hist[base + j] : 0; loc += v[j]; }
    s[t] = loc;
    __syncthreads();
    for (int off = 1; off < 256; off <<= 1) {
        int u = (t >= off) ? s[t - off] : 0;
        __syncthreads();
        s[t] += u;
        __syncthreads();
    }
    int run = boff[blockIdx.x] + s[t] - loc;
#pragma unroll
    for (int j = 0; j < 4; ++j) {
        if (base + j < N) {
            row_off[base + j] = run;
            dinv[base + j] = rsqrtf((float)(v[j] + 1));
        }
        run += v[j];
    }
}

__global__ void k_bin(const int* __restrict__ src, const int* __restrict__ dst,
                      const int* __restrict__ row_off, int* __restrict__ cursor,
                      const float* __restrict__ dinv,
                      int* __restrict__ csr_src, float* __restrict__ csr_w, int E) {
    int i = blockIdx.x * blockDim.x + threadIdx.x;
    if (i >= E) return;
    int d = dst[i], s = src[i];
    int pos = row_off[d] + atomicAdd(&cursor[d], 1);
    csr_src[pos] = s;
    csr_w[pos] = dinv[s] * dinv[d];
}

// fused preprocessing, block-range partitioned:
//   blocks [0,11):        head-weight collapse (WcT = (W3@W4@W5)^T, bc chain)
//   blocks [11,11+nfo):   fill d_out (out + out_emb) with -inf for atomic-max
//   blocks [11+nfo, ...): x->bf16, W1^T->bf16, W2^T->bf16
__global__ __launch_bounds__(256) void k_pre(
        const float* __restrict__ W3, const float* __restrict__ W4,
        const float* __restrict__ W5, const float* __restrict__ b3,
        const float* __restrict__ b4, const float* __restrict__ b5,
        float* __restrict__ WcT, float* __restrict__ bc,
        unsigned* __restrict__ outp, int nout, int nfo,
        const float* __restrict__ x, unsigned short* __restrict__ xb, int n4,
        const float* __restrict__ W1, unsigned short* __restrict__ w1t, int K1, int N1,
        const float* __restrict__ W2, unsigned short* __restrict__ w2t, int K2, int N2) {
    int b = blockIdx.x;
    int t = threadIdx.x;
    if (b < 11) {
        int c = b;
        if (c < 10) {
            __shared__ float Tc[128];
            if (t < 128) {
                float s = 0.f;
#pragma unroll 8
                for (int k = 0; k < 32; ++k) s = fmaf(W4[t * 32 + k], W5[k * 10 + c], s);
                Tc[t] = s;
            }
            __syncthreads();
            float s = 0.f;
            const float* w3r = &W3[t * 128];
#pragma unroll 8
            for (int j = 0; j < 128; ++j) s = fmaf(w3r[j], Tc[j], s);
            WcT[c * 256 + t] = s;
        } else {
            __shared__ float v[32];
            if (t < 32) {
                float s = b4[t];
                for (int j = 0; j < 128; ++j) s = fmaf(b3[j], W4[j * 32 + t], s);
                v[t] = s;
            }
            __syncthreads();
            if (t < 10) {
                float s = b5[t];
                for (int k = 0; k < 32; ++k) s = fmaf(v[k], W5[k * 10 + t], s);
                bc[t] = s;
            }
        }
        return;
    }
    if (b < 11 + nfo) {
        int i = (b - 11) * 256 + t;
        if (i < nout) outp[i] = 0xff800000u;   // -inf
        return;
    }
    int i = (b - 11 - nfo) * 256 + t;
    if (i < n4) {
        float4 v = ((const float4*)x)[i];
        ushort4 o;
        o.x = f2b(v.x); o.y = f2b(v.y); o.z = f2b(v.z); o.w = f2b(v.w);
        ((ushort4*)xb)[i] = o;
        return;
    }
    i -= n4;
    if (i < K1 * N1) {
        int k = i / N1, n = i % N1;
        w1t[(size_t)n * K1 + k] = f2b(W1[i]);
        return;
    }
    i -= K1 * N1;
    if (i < K2 * N2) {
        int k = i / N2, n = i % N2;
        w2t[(size_t)n * K2 + k] = f2b(W2[i]);
    }
}

// gather-aggregate over dst-CSR, bf16 in/out.
// Uniform ILP-6 predicated edge loop: always 6 gathers in flight; out-of-range
// slots clamp to the last edge (L1-hit) with weight 0 (exact no-op FMA).
template <int F>
__global__ __launch_bounds__(256) void k_gather_b(const unsigned short* __restrict__ H,
        const int* __restrict__ row_off, const int* __restrict__ csr_src,
        const float* __restrict__ csr_w, const float* __restrict__ dinv,
        const float* __restrict__ bias, unsigned short* __restrict__ outb, int N) {
    const int LPN = F / 8;
    const int NPB = 256 / LPN;
    int node = blockIdx.x * NPB + threadIdx.x / LPN;
    if (node >= N) return;
    int f = (threadIdx.x % LPN) * 8;
    const unsigned short* Hf = H + f;
    float sc = dinv[node]; sc *= sc;
    float a[8];
    cvt8(*(const uint4*)&Hf[(size_t)node * F], a);
#pragma unroll
    for (int j = 0; j < 8; ++j) a[j] *= sc;
    if (bias) {
#pragma unroll
        for (int j = 0; j < 8; ++j) a[j] += bias[f + j];
    }
    int e0 = row_off[node], e1 = row_off[node + 1];
    int ee = e1 - 1;
    for (int e = e0; e < e1; e += 6) {
        int i0 = e;
        int i1 = min(e + 1, ee), i2 = min(e + 2, ee), i3 = min(e + 3, ee);
        int i4 = min(e + 4, ee), i5 = min(e + 5, ee);
        int s0 = csr_src[i0], s1 = csr_src[i1], s2 = csr_src[i2];
        int s3 = csr_src[i3], s4 = csr_src[i4], s5 = csr_src[i5];
        float w0 = csr_w[i0];
        float w1 = (e + 1 <= ee) ? csr_w[i1] : 0.f;
        float w2 = (e + 2 <= ee) ? csr_w[i2] : 0.f;
        float w3 = (e + 3 <= ee) ? csr_w[i3] : 0.f;
        float w4 = (e + 4 <= ee) ? csr_w[i4] : 0.f;
        float w5 = (e + 5 <= ee) ? csr_w[i5] : 0.f;
        uint4 v0 = *(const uint4*)&Hf[(size_t)s0 * F];
        uint4 v1 = *(const uint4*)&Hf[(size_t)s1 * F];
        uint4 v2 = *(const uint4*)&Hf[(size_t)s2 * F];
        uint4 v3 = *(const uint4*)&Hf[(size_t)s3 * F];
        uint4 v4 = *(const uint4*)&Hf[(size_t)s4 * F];
        uint4 v5 = *(const uint4*)&Hf[(size_t)s5 * F];
        float bb[8];
        cvt8(v0, bb);
#pragma unroll
        for (int j = 0; j < 8; ++j) a[j] = fmaf(w0, bb[j], a[j]);
        cvt8(v1, bb);
#pragma unroll
        for (int j = 0; j < 8; ++j) a[j] = fmaf(w1, bb[j], a[j]);
        cvt8(v2, bb);
#pragma unroll
        for (int j = 0; j < 8; ++j) a[j] = fmaf(w2, bb[j], a[j]);
        cvt8(v3, bb);
#pragma unroll
        for (int j = 0; j < 8; ++j) a[j] = fmaf(w3, bb[j], a[j]);
        cvt8(v4, bb);
#pragma unroll
        for (int j = 0; j < 8; ++j) a[j] = fmaf(w4, bb[j], a[j]);
        cvt8(v5, bb);
#pragma unroll
        for (int j = 0; j < 8; ++j) a[j] = fmaf(w5, bb[j], a[j]);
    }
    uint4 o;
    o.x = (unsigned)f2b(a[0]) | ((unsigned)f2b(a[1]) << 16);
    o.y = (unsigned)f2b(a[2]) | ((unsigned)f2b(a[3]) << 16);
    o.z = (unsigned)f2b(a[4]) | ((unsigned)f2b(a[5]) << 16);
    o.w = (unsigned)f2b(a[6]) | ((unsigned)f2b(a[7]) << 16);
    *(uint4*)&outb[(size_t)node * F + f] = o;
}

// terminal fused kernel: gather layer-2 aggregate (F=256, 8 nodes/block,
// 32 lanes/node), then — with h2 still in registers —
//   z = h2 @ Wc + bc  -> shfl-reduce -> run-coalesced atomicMaxF into out[g,:10]
//   feature-wise segment_max of h2 via LDS tile -> atomicMaxF into out_emb[g,:256]
// h2 is never written to global; out/out_emb must be pre-filled with -inf.
__global__ __launch_bounds__(256) void k_gather_head(
        const unsigned short* __restrict__ H,
        const int* __restrict__ row_off, const int* __restrict__ csr_src,
        const float* __restrict__ csr_w, const float* __restrict__ dinv,
        const float* __restrict__ bias, const int* __restrict__ batch,
        const float* __restrict__ WcT, const float* __restrict__ bc,
        float* __restrict__ out, float* __restrict__ out_emb, int N) {
    __shared__ __align__(16) float Ws[10][260];
    __shared__ float bs[10];
    __shared__ __align__(16) float h2s[8][264];
    __shared__ float zl[8][10];
    __shared__ int gl[8];
    int t = threadIdx.x;
    for (int i = t; i < 2560; i += 256) Ws[i >> 8][i & 255] = WcT[i];
    if (t < 10) bs[t] = bc[t];
    int nl = t >> 5;          // node within block, 0..7
    int q  = t & 31;          // lane within node group
    int node = blockIdx.x * 8 + nl;
    bool valid = node < N;
    if (q == 0) gl[nl] = valid ? batch[node] : -1;
    int f = q * 8;
    const unsigned short* Hf = H + f;
    float a[8] = {0.f, 0.f, 0.f, 0.f, 0.f, 0.f, 0.f, 0.f};
    if (valid) {
        float sc = dinv[node]; sc *= sc;
        cvt8(*(const uint4*)&Hf[(size_t)node * 256], a);
#pragma unroll
        for (int j = 0; j < 8; ++j) a[j] = fmaf(a[j], sc, bias[f + j]);
        int e0 = row_off[node], e1 = row_off[node + 1];
        int ee = e1 - 1;
        for (int e = e0; e < e1; e += 6) {
            int i0 = e;
            int i1 = min(e + 1, ee), i2 = min(e + 2, ee), i3 = min(e + 3, ee);
            int i4 = min(e + 4, ee), i5 = min(e + 5, ee);
            int s0 = csr_src[i0], s1 = csr_src[i1], s2 = csr_src[i2];
            int s3 = csr_src[i3], s4 = csr_src[i4], s5 = csr_src[i5];
            float w0 = csr_w[i0];
            float w1 = (e + 1 <= ee) ? csr_w[i1] : 0.f;
            float w2 = (e + 2 <= ee) ? csr_w[i2] : 0.f;
            float w3 = (e + 3 <= ee) ? csr_w[i3] : 0.f;
            float w4 = (e + 4 <= ee) ? csr_w[i4] : 0.f;
            float w5 = (e + 5 <= ee) ? csr_w[i5] : 0.f;
            uint4 v0 = *(const uint4*)&Hf[(size_t)s0 * 256];
            uint4 v1 = *(const uint4*)&Hf[(size_t)s1 * 256];
            uint4 v2 = *(const uint4*)&Hf[(size_t)s2 * 256];
            uint4 v3 = *(const uint4*)&Hf[(size_t)s3 * 256];
            uint4 v4 = *(const uint4*)&Hf[(size_t)s4 * 256];
            uint4 v5 = *(const uint4*)&Hf[(size_t)s5 * 256];
            float bb[8];
            cvt8(v0, bb);
#pragma unroll
            for (int j = 0; j < 8; ++j) a[j] = fmaf(w0, bb[j], a[j]);
            cvt8(v1, bb);
#pragma unroll
            for (int j = 0; j < 8; ++j) a[j] = fmaf(w1, bb[j], a[j]);
            cvt8(v2, bb);
#pragma unroll
            for (int j = 0; j < 8; ++j) a[j] = fmaf(w2, bb[j], a[j]);
            cvt8(v3, bb);
#pragma unroll
            for (int j = 0; j < 8; ++j) a[j] = fmaf(w3, bb[j], a[j]);
            cvt8(v4, bb);
#pragma unroll
            for (int j = 0; j < 8; ++j) a[j] = fmaf(w4, bb[j], a[j]);
            cvt8(v5, bb);
#pragma unroll
            for (int j = 0; j < 8; ++j) a[j] = fmaf(w5, bb[j], a[j]);
        }
    }
    __syncthreads();   // Ws/bs staged (and gl visible)

    // head dots: p[c] = sum over this lane's 8 features
#pragma unroll
    for (int c = 0; c < 10; ++c) {
        float4 wa = *(const float4*)&Ws[c][f];
        float4 wb = *(const float4*)&Ws[c][f + 4];
        float s = a[0] * wa.x;
        s = fmaf(a[1], wa.y, s);
        s = fmaf(a[2], wa.z, s);
        s = fmaf(a[3], wa.w, s);
        s = fmaf(a[4], wb.x, s);
        s = fmaf(a[5], wb.y, s);
        s = fmaf(a[6], wb.z, s);
        s = fmaf(a[7], wb.w, s);
        // sum across the node's 32 lanes (masks <32 stay within the group)
        s += __shfl_xor(s, 16);
        s += __shfl_xor(s, 8);
        s += __shfl_xor(s, 4);
        s += __shfl_xor(s, 2);
        s += __shfl_xor(s, 1);
        if (q == 0) zl[nl][c] = s + bs[c];
    }
    // stage h2 tile for feature-wise reduction
    *(float4*)&h2s[nl][f]     = make_float4(a[0], a[1], a[2], a[3]);
    *(float4*)&h2s[nl][f + 4] = make_float4(a[4], a[5], a[6], a[7]);
    __syncthreads();

    // out_emb: thread t owns feature t; run-coalesced atomics (batch-sorted)
    {
        int curg = -1; float m = 0.f;
#pragma unroll
        for (int n = 0; n < 8; ++n) {
            int g = gl[n];
            if (g < 0) continue;
            float v = h2s[n][t];
            if (g != curg) {
                if (curg >= 0) atomicMaxF(&out_emb[(size_t)curg * 256 + t], m);
                curg = g; m = v;
            } else {
                m = fmaxf(m, v);
            }
        }
        if (curg >= 0) atomicMaxF(&out_emb[(size_t)curg * 256 + t], m);
    }
    // out: thread t<10 owns head column t
    if (t < 10) {
        int curg = -1; float m = 0.f;
#pragma unroll
        for (int n = 0; n < 8; ++n) {
            int g = gl[n];
            if (g < 0) continue;
            float v = zl[n][t];
            if (g != curg) {
                if (curg >= 0) atomicMaxF(&out[(size_t)curg * 10 + t], m);
                curg = g; m = v;
            } else {
                m = fmaxf(m, v);
            }
        }
        if (curg >= 0) atomicMaxF(&out[(size_t)curg * 10 + t], m);
    }
}

// bf16 MFMA GEMM, fat-N tile: 128x256 per block, 512 threads = 8 waves (2x4),
// each wave 64x64 via 4x4 grid of 16x16x32 MFMAs, BK=64, global_load_lds w16,
// XOR-swizzled LDS, operand-swap mfma (lane = row + 4 contiguous cols).
template <int OUT_BF16, int ACT>
__global__ __launch_bounds__(512) void k_gemm_mfma256(const unsigned short* __restrict__ A,
        const unsigned short* __restrict__ Bt, const float* __restrict__ bias,
        void* __restrict__ Cout, int M, int K, int NC) {
    __shared__ __align__(16) unsigned short As[128][64];   // 16 KB
    __shared__ __align__(16) unsigned short Bs[256][64];   // 32 KB
    int tid = threadIdx.x;
    int wave = tid >> 6, lane = tid & 63;
    int row0 = blockIdx.y * 128, col0 = blockIdx.x * 256;
    int wr = (wave >> 2) * 64, wc = (wave & 3) * 64;
    f32x4 acc[4][4] = {};
    int lr = lane & 15;
    int lg = lane >> 4;
    int sw = ((lane & 7) ^ (lane >> 3)) << 3;
    int ch0 = (lg ^ (lr & 7)) << 3;
    int ch1 = ch0 ^ (4 << 3);

    for (int k0 = 0; k0 < K; k0 += 64) {
        // stage A: 2 rounds x (8 waves x 8 rows), B: 4 rounds
#pragma unroll
        for (int c = 0; c < 2; ++c) {
            int rl = c * 64 + wave * 8 + (lane >> 3);
            int gr = min(row0 + rl, M - 1);
            gl16(&As[c * 64 + wave * 8][0], &A[(size_t)gr * K + k0 + sw]);
        }
#pragma unroll
        for (int c = 0; c < 4; ++c) {
            int rl = c * 64 + wave * 8 + (lane >> 3);
            gl16(&Bs[c * 64 + wave * 8][0], &Bt[(size_t)(col0 + rl) * K + k0 + sw]);
        }
        __syncthreads();
        bf16x8 af[2][4], bv[2][4];
#pragma unroll
        for (int i = 0; i < 4; ++i) {
            int ra = wr + i * 16 + lr;
            int rb = wc + i * 16 + lr;
            af[0][i] = *(const bf16x8*)&As[ra][ch0];
            af[1][i] = *(const bf16x8*)&As[ra][ch1];
            bv[0][i] = *(const bf16x8*)&Bs[rb][ch0];
            bv[1][i] = *(const bf16x8*)&Bs[rb][ch1];
        }
#pragma unroll
        for (int s = 0; s < 2; ++s)
#pragma unroll
            for (int i = 0; i < 4; ++i)
#pragma unroll
                for (int j = 0; j < 4; ++j)
                    acc[i][j] = __builtin_amdgcn_mfma_f32_16x16x32_bf16(bv[s][j], af[s][i], acc[i][j], 0, 0, 0);
        __syncthreads();
    }

    int q4 = lg * 4;
    float4 bb[4];
#pragma unroll
    for (int j = 0; j < 4; ++j)
        bb[j] = bias ? *(const float4*)&bias[col0 + wc + j * 16 + q4]
                     : make_float4(0.f, 0.f, 0.f, 0.f);
#pragma unroll
    for (int i = 0; i < 4; ++i) {
        int row = row0 + wr + i * 16 + lr;
        if (row >= M) continue;
#pragma unroll
        for (int j = 0; j < 4; ++j) {
            int c0 = col0 + wc + j * 16 + q4;
            float4 v;
            v.x = acc[i][j][0] + bb[j].x;
            v.y = acc[i][j][1] + bb[j].y;
            v.z = acc[i][j][2] + bb[j].z;
            v.w = acc[i][j][3] + bb[j].w;
            if (ACT) {
                v.x = (v.x >= 0.f) ? v.x : 0.01f * v.x;
                v.y = (v.y >= 0.f) ? v.y : 0.01f * v.y;
                v.z = (v.z >= 0.f) ? v.z : 0.01f * v.z;
                v.w = (v.w >= 0.f) ? v.w : 0.01f * v.w;
            }
            if (OUT_BF16) {
                uint2 o;
                o.x = (unsigned)f2b(v.x) | ((unsigned)f2b(v.y) << 16);
                o.y = (unsigned)f2b(v.z) | ((unsigned)f2b(v.w) << 16);
                *(uint2*)&((unsigned short*)Cout)[(size_t)row * NC + c0] = o;
            } else {
                *(float4*)&((float*)Cout)[(size_t)row * NC + c0] = v;
            }
        }
    }
}

extern "C" void kernel_launch(void* const* d_in, const int* in_sizes, int n_in,
                              void* d_out, int out_size, void* d_ws, size_t ws_size,
                              hipStream_t stream) {
    const float* x  = (const float*)d_in[0];
    const int* ei   = (const int*)d_in[1];
    const int* batch= (const int*)d_in[2];
    const float* W1 = (const float*)d_in[3];
    const float* b1 = (const float*)d_in[4];
    const float* W2 = (const float*)d_in[5];
    const float* b2 = (const float*)d_in[6];
    const float* W3 = (const float*)d_in[7];
    const float* b3 = (const float*)d_in[8];
    const float* W4 = (const float*)d_in[9];
    const float* b4 = (const float*)d_in[10];
    const float* W5 = (const float*)d_in[11];
    const float* b5 = (const float*)d_in[12];

    const int N  = in_sizes[2];           // 50000
    const int F  = in_sizes[0] / N;       // 128
    const int E  = in_sizes[1] / 2;       // 400000
    const int C1 = in_sizes[4];           // 512
    const int C2 = in_sizes[6];           // 256
    const int C5 = in_sizes[12];          // 10
    const int G  = out_size / (C2 + C5);  // 512
    const int NB = DIV_UP(N, 1024);

    const int* srcp = ei;
    const int* dstp = ei + E;

    // ---- workspace layout (256B-aligned carve-outs) ----
    uintptr_t p = (uintptr_t)d_ws;
    auto carve = [&](size_t bytes) {
        uintptr_t r = p;
        p += (bytes + 255) & ~(size_t)255;
        return (void*)r;
    };
    int* hist    = (int*)carve(sizeof(int) * N);
    int* cursor  = (int*)carve(sizeof(int) * N);      // MUST follow hist (joint zero-fill)
    int* row_off = (int*)carve(sizeof(int) * (N + 1));
    int* bsum    = (int*)carve(sizeof(int) * NB);
    int* boff    = (int*)carve(sizeof(int) * NB);
    int* csr_src = (int*)carve(sizeof(int) * E);
    float* csr_w = (float*)carve(sizeof(float) * E);
    float* dinv  = (float*)carve(sizeof(float) * N);
    float* wct   = (float*)carve(sizeof(float) * C2 * C5);
    float* bcv   = (float*)carve(sizeof(float) * C5);
    unsigned short* w1t = (unsigned short*)carve(sizeof(short) * F * C1);
    unsigned short* w2t = (unsigned short*)carve(sizeof(short) * C1 * C2);
    unsigned short* xb    = (unsigned short*)carve(sizeof(short) * (size_t)N * F);
    unsigned short* aggxb = (unsigned short*)carve(sizeof(short) * (size_t)N * F);
    unsigned short* h1b   = (unsigned short*)carve(sizeof(short) * (size_t)N * C1);
    unsigned short* t2b   = (unsigned short*)carve(sizeof(short) * (size_t)N * C2);

    float* out     = (float*)d_out;
    float* out_emb = out + (size_t)G * C5;

    // ---- CSR build + fused preprocessing ----
    int zspan = (int)(((sizeof(int) * N + 255) & ~(size_t)255) / 4) + N;  // hist..cursor
    k_zero_i<<<DIV_UP(zspan, 256), 256, 0, stream>>>(hist, zspan);
    k_hist<<<DIV_UP(E, 256), 256, 0, stream>>>(dstp, hist, E);
    k_scan_bsum<<<NB, 256, 0, stream>>>(hist, bsum, N);
    k_scan_boff<<<1, 1024, 0, stream>>>(bsum, boff, row_off, NB, N);
    k_scan_apply<<<NB, 256, 0, stream>>>(hist, boff, row_off, dinv, N);
    k_bin<<<DIV_UP(E, 256), 256, 0, stream>>>(srcp, dstp, row_off, cursor, dinv,
                                              csr_src, csr_w, E);

    int n4 = N * F / 4;
    int nout = G * (C2 + C5);
    int nfo = DIV_UP(nout, 256);
    int prep_total = n4 + F * C1 + C1 * C2;
    int pre_blocks = 11 + nfo + DIV_UP(prep_total, 256);
    k_pre<<<pre_blocks, 256, 0, stream>>>(W3, W4, W5, b3, b4, b5, wct, bcv,
                                          (unsigned*)d_out, nout, nfo,
                                          x, xb, n4, W1, w1t, F, C1, W2, w2t, C1, C2);

    // ---- layer 1: gather (bf16) -> fat-N MFMA GEMM + bias + leakyrelu -> h1 bf16 ----
    k_gather_b<128><<<DIV_UP(N, 16), 256, 0, stream>>>(
        xb, row_off, csr_src, csr_w, dinv, nullptr, aggxb, N);
    dim3 g1(C1 / 256, DIV_UP(N, 128));
    k_gemm_mfma256<1, 1><<<g1, 512, 0, stream>>>(aggxb, w1t, b1, h1b, N, F, C1);

    // ---- layer 2: fat-N MFMA GEMM -> t2 bf16 ----
    dim3 g2(C2 / 256, DIV_UP(N, 128));
    k_gemm_mfma256<1, 0><<<g2, 512, 0, stream>>>(h1b, w2t, nullptr, t2b, N, C1, C2);

    // ---- terminal fused: gather(+b2) -> head dots -> both segment_maxes ----
    k_gather_head<<<DIV_UP(N, 8), 256, 0, stream>>>(
        t2b, row_off, csr_src, csr_w, dinv, b2, batch, wct, bcv,
        out, out_emb, N);
}